// Round 19
// baseline (307.857 us; speedup 1.0000x reference)
//
#include <hip/hip_runtime.h>
#include <math.h>

#define S 256
#define NB 4
#define TAU 0.1f
#define KSEL 128
#define LOG_TAB 21
#define TAB_SZ (1u << LOG_TAB)
#define TAB_MASK (TAB_SZ - 1)
#define EMPTY64 0xFFFFFFFFFFFFFFFFull
#define BMQ_WORDS (1u << 20)  // 4*32^3 bricks * 8 u64 words = 8MB
#define NBINS 8192
#define BIN_BASE 0x3D800      // (0x3D800000 >> 12), conf floor 0.0625 < TAU
#define CAND_CAP 4096
#define CPAD 32               // ints per counter slot -> one 128B line each

typedef unsigned long long u64;
typedef unsigned int u32;
typedef unsigned char u8;

__device__ __forceinline__ u32 hash_key(int key) {
    u32 h = (u32)key * 0x9E3779B1u;
    h ^= h >> 15;
    return h & TAB_MASK;
}

__device__ __forceinline__ int conf_bin(float conf) {
    int bin = (int)(__float_as_uint(conf) >> 12) - BIN_BASE;
    return bin < 0 ? 0 : (bin > NBINS - 1 ? NBINS - 1 : bin);
}

__device__ __forceinline__ int tab_lookup(const u64* __restrict__ tab, int key) {
    u32 slot = hash_key(key);
    for (;;) {
        u64 e = tab[slot];
        if ((u32)(e >> 32) == (u32)key) return (int)(u32)e;
        if (e == EMPTY64) return -1;
        slot = (slot + 1) & TAB_MASK;
    }
}

// ---- desc row body: register staging (cached loads) + uniform-W GEMV ----
__device__ __forceinline__ void desc_row(const float* __restrict__ feats,
                                         const float* __restrict__ W,
                                         const float* __restrict__ bias,
                                         float* __restrict__ voxel_desc, int i, int N) {
    if (i >= N) return;
    const float4* row4 = (const float4*)(feats + (size_t)i * 64);
    float4 r[16];
    #pragma unroll
    for (int k = 0; k < 16; k++) r[k] = row4[k];
    __builtin_amdgcn_sched_barrier(0);   // keep loads issued before compute
    float acc[32];
    #pragma unroll
    for (int d = 0; d < 32; d++) acc[d] = bias[d];
    #pragma unroll
    for (int k = 0; k < 16; k++) {
        float4 f = r[k];
        const float* Wb = W + k * 4 * 32;   // thread-uniform -> scalar loads
        #pragma unroll
        for (int d = 0; d < 32; d++) {
            acc[d] = fmaf(f.x, Wb[d], acc[d]);
            acc[d] = fmaf(f.y, Wb[32 + d], acc[d]);
            acc[d] = fmaf(f.z, Wb[64 + d], acc[d]);
            acc[d] = fmaf(f.w, Wb[96 + d], acc[d]);
        }
    }
    float ss = 0.f;
    #pragma unroll
    for (int d = 0; d < 32; d++) ss += acc[d] * acc[d];
    float inv = 1.0f / fmaxf(sqrtf(ss), 1e-12f);
    float4* out4 = (float4*)(voxel_desc + (size_t)i * 32);
    #pragma unroll
    for (int q = 0; q < 8; q++) {
        float4 o;
        o.x = acc[q * 4 + 0] * inv; o.y = acc[q * 4 + 1] * inv;
        o.z = acc[q * 4 + 2] * inv; o.w = acc[q * 4 + 3] * inv;
        out4[q] = o;   // thread writes exactly its own 128B line
    }
}

// ---- insert body: CAS-first insert + exact rep-flag tracking + brick bitmap ----
__device__ __forceinline__ void insert_pt(const int* __restrict__ coords,
                                          const float* __restrict__ scores,
                                          u64* __restrict__ tab, u64* __restrict__ bmq,
                                          u8* __restrict__ claimed, u32* __restrict__ dlist,
                                          int* __restrict__ dcnt, int i, int N) {
    if (i >= N) return;
    int4 c = ((const int4*)coords)[i];
    float conf = scores[i];
    int key = ((c.x * S + c.y) * S + c.z) * S + c.w;
    if (conf > TAU) {
        int brick = (((c.x << 5) + (c.y >> 3)) * 32 + (c.z >> 3)) * 32 + (c.w >> 3);
        u64 bit = 1ull << (((c.z & 7) << 3) | (c.w & 7));
        atomicOr(&bmq[(size_t)brick * 8 + (c.y & 7)], bit);
    }
    u64 ins = ((u64)(u32)key << 32) | (u32)i;
    u32 slot = hash_key(key);
    for (;;) {
        u64 prev = atomicCAS(&tab[slot], EMPTY64, ins);
        if (prev == EMPTY64) { claimed[i] = 1; return; }    // claimed empty slot
        if ((u32)(prev >> 32) == (u32)key) {
            u64 old = atomicMin(&tab[slot], ins);
            if ((u32)old > (u32)i) {                        // displaced larger-index rep
                claimed[i] = 1;
                int p = atomicAdd(dcnt, 1);
                dlist[p] = (u32)old;
            }
            return;
        }
        slot = (slot + 1) & TAB_MASK;                       // different key: probe on
    }
}

// Clear flags of displaced former reps (runs between the two fat kernels).
__global__ void k_fixrep(const u32* __restrict__ dlist, const int* __restrict__ dcnt,
                         u8* __restrict__ claimed) {
    int n = *dcnt;
    for (int t = blockIdx.x * blockDim.x + threadIdx.x; t < n; t += gridDim.x * blockDim.x)
        claimed[dlist[t]] = 0;
}

// Fused: role-interleaved insert (2 of 3 blocks) + desc first-half (1 of 3).
__global__ __launch_bounds__(256, 4) void k_ins_desc(const int* __restrict__ coords,
        const float* __restrict__ scores, u64* __restrict__ tab, u64* __restrict__ bmq,
        u8* __restrict__ claimed, u32* __restrict__ dlist, int* __restrict__ dcnt,
        const float* __restrict__ feats, const float* __restrict__ W,
        const float* __restrict__ bias, float* __restrict__ voxel_desc,
        int N, int nIns, int nDesc, int descRow0) {
    int g = blockIdx.x / 3, r = blockIdx.x % 3;
    if (r < 2) {
        int ib = g * 2 + r;
        if (ib >= nIns) return;
        insert_pt(coords, scores, tab, bmq, claimed, dlist, dcnt,
                  ib * 256 + threadIdx.x, N);
    } else {
        if (g >= nDesc) return;
        desc_row(feats, W, bias, voxel_desc, descRow0 + g * 256 + threadIdx.x, N);
    }
}

// ---- peak body: coalesced rep-flag + window-mask brick gather + sparse probes.
// Histogram build moved OUT to k_hist (removes hot-bin atomic chains from the
// latency-critical kernel). ----
__device__ __forceinline__ void peak_block(const int* __restrict__ coords,
        const float* __restrict__ scores, const u64* __restrict__ tab,
        const u64* __restrict__ bmq, const u8* __restrict__ claimed,
        u64* __restrict__ peaks, int* __restrict__ cnt,
        int N, int pcap, int pb) {
    int i = pb * 256 + threadIdx.x;
    bool alive = (i < N);
    int ii = alive ? i : 0;
    int4 c = ((const int4*)coords)[ii];
    float conf = alive ? scores[ii] : -1.0f;
    bool isrep = claimed[ii] != 0;   // coalesced byte read (exact rep-ness)
    int X = c.y, Y = c.z, Z = c.w;
    int kb = ((c.x * S + X) * S + Y) * S + Z;
    bool ispeak = false;
    if (alive && conf > TAU) {
        // own-cell contribution: rep-majority needs NO tab lookup
        float hmax = isrep ? conf : scores[tab_lookup(tab, kb)];
        int ylo = Y > 0 ? Y - 1 : 0, yhi = Y < S - 1 ? Y + 1 : S - 1;
        int zlo = Z > 0 ? Z - 1 : 0, zhi = Z < S - 1 ? Z + 1 : S - 1;
        int by0 = ylo >> 3, by1 = yhi >> 3, bz0 = zlo >> 3, bz1 = zhi >> 3;
        #pragma unroll
        for (int dx = -1; dx <= 1; dx++) {
            int nx = X + dx;
            if ((unsigned)nx >= S) continue;
            int bx = nx >> 3, wsel = nx & 7;
            for (int by = by0; by <= by1; by++) {
                int rlo = ylo > by * 8 ? ylo : by * 8;
                int rhi = yhi < by * 8 + 7 ? yhi : by * 8 + 7;
                int nrow = rhi - rlo + 1;          // 1..3
                u64 span = (nrow == 1 ? 0x01ull : nrow == 2 ? 0x0101ull : 0x010101ull)
                           << ((rlo & 7) * 8);
                for (int bz = bz0; bz <= bz1; bz++) {
                    int clo = zlo > bz * 8 ? zlo : bz * 8;
                    int chi = zhi < bz * 8 + 7 ? zhi : bz * 8 + 7;
                    u32 zbits = ((1u << (chi - clo + 1)) - 1) << (clo & 7);
                    u64 mask = (u64)zbits * span;   // rows rlo..rhi, cols clo..chi
                    u64 word = bmq[(size_t)((((c.x << 5) + bx) * 32 + by) * 32 + bz) * 8 + wsel];
                    u64 mm = word & mask;
                    if (dx == 0 && (Y >> 3) == by && (Z >> 3) == bz)
                        mm &= ~(1ull << (((Y & 7) << 3) | (Z & 7)));   // own bit done above
                    while (mm) {
                        int p = __builtin_ctzll(mm);
                        mm &= mm - 1;
                        int ny = (by << 3) | (p >> 3), nz = (bz << 3) | (p & 7);
                        int j = tab_lookup(tab, ((c.x * S + nx) * S + ny) * S + nz);
                        if (j >= 0) hmax = fmaxf(hmax, scores[j]);
                    }
                }
            }
        }
        ispeak = (hmax == conf);
    }

    __shared__ int wcnt[4][NB];
    __shared__ int bbase[NB];
    int w = threadIdx.x >> 6;
    int lane = threadIdx.x & 63;
    u64 lmask_lt = (lane == 63) ? 0x7FFFFFFFFFFFFFFFull : ((1ull << lane) - 1ull);
    u64 mb[NB];
    #pragma unroll
    for (int b = 0; b < NB; b++) {
        mb[b] = __ballot(ispeak && (c.x == b));
        if (lane == 0) wcnt[w][b] = __popcll(mb[b]);
    }
    __syncthreads();
    if (threadIdx.x < NB) {
        int b = threadIdx.x;
        int tot = wcnt[0][b] + wcnt[1][b] + wcnt[2][b] + wcnt[3][b];
        bbase[b] = tot > 0 ? atomicAdd(&cnt[b * CPAD], tot) : 0;
    }
    __syncthreads();
    if (ispeak) {
        int b = c.x;
        int pre = 0;
        for (int w2 = 0; w2 < w; w2++) pre += wcnt[w2][b];
        int rank = __popcll(mb[b] & lmask_lt);
        int pidx = bbase[b] + pre + rank;
        if (pidx < pcap)
            peaks[(size_t)b * pcap + pidx] =
                ((u64)__float_as_uint(conf) << 32) | (u32)(~(u32)i);
    }
}

// Fused: role-interleaved peak (2 of 3 blocks) + desc second-half (1 of 3).
__global__ __launch_bounds__(256, 4) void k_peak_desc(const int* __restrict__ coords,
        const float* __restrict__ scores, const u64* __restrict__ tab,
        const u64* __restrict__ bmq, const u8* __restrict__ claimed,
        u64* __restrict__ peaks, int* __restrict__ cnt,
        const float* __restrict__ feats,
        const float* __restrict__ W, const float* __restrict__ bias,
        float* __restrict__ voxel_desc, int N, int pcap,
        int nPeak, int nDesc, int descRow0) {
    int g = blockIdx.x / 3, r = blockIdx.x % 3;
    if (r < 2) {
        int pb = g * 2 + r;
        if (pb >= nPeak) return;
        peak_block(coords, scores, tab, bmq, claimed, peaks, cnt, N, pcap, pb);
    } else {
        if (g >= nDesc) return;
        desc_row(feats, W, bias, voxel_desc, descRow0 + g * 256 + threadIdx.x, N);
    }
}

// Dedicated histogram build over compacted peaks (dense sequential reads,
// full occupancy, no co-resident latency role to extend).
__global__ void k_hist(const u64* __restrict__ peaks, const int* __restrict__ cnt,
                       int* __restrict__ hist, int pcap) {
    for (int b = 0; b < NB; b++) {
        int n = cnt[b * CPAD]; if (n > pcap) n = pcap;
        for (int t = blockIdx.x * blockDim.x + threadIdx.x; t < n;
             t += gridDim.x * blockDim.x) {
            float conf = __uint_as_float((u32)(peaks[(size_t)b * pcap + t] >> 32));
            atomicAdd(&hist[b * NBINS + conf_bin(conf)], 1);
        }
    }
}

// One block; wave b finds per-batch threshold bin (count of bins >= thr covers K).
__global__ void k_thresh(const int* __restrict__ hist, const int* __restrict__ cnt,
                         u32* __restrict__ thrbin, int pcap) {
    int w = threadIdx.x >> 6;
    int lane = threadIdx.x & 63;
    if (w >= NB) return;
    int n = cnt[w * CPAD]; if (n > pcap) n = pcap;
    int need = n < KSEL ? n : KSEL;
    const int* h = hist + w * NBINS;
    int running = 0;
    u32 thr = 0;
    for (int hi = NBINS - 64; hi >= 0; hi -= 64) {
        int v = h[hi + lane];
        int s = v;
        #pragma unroll
        for (int off = 1; off < 64; off <<= 1) {
            int o = __shfl_down(s, off);
            if (lane + off < 64) s += o;
        }
        int csum = __shfl(s, 0);
        if (running + csum >= need) {
            u64 m = __ballot(running + s >= need);
            int top = 63 - __builtin_clzll(m);
            thr = (u32)(hi + top);
            break;
        }
        running += csum;
    }
    if (lane == 0) thrbin[w] = thr;
}

__global__ void k_compact(const u64* __restrict__ peaks, const int* __restrict__ cnt,
                          const u32* __restrict__ thrbin, u64* __restrict__ cand,
                          int* __restrict__ ccnt, int pcap) {
    int t = blockIdx.x * blockDim.x + threadIdx.x;
    int b = t / pcap;
    if (b >= NB) return;
    int e = t % pcap;
    int n = cnt[b * CPAD]; if (n > pcap) n = pcap;
    if (e >= n) return;
    u64 key = peaks[(size_t)b * pcap + e];
    float conf = __uint_as_float((u32)(key >> 32));
    if (conf_bin(conf) >= (int)thrbin[b]) {
        int p = atomicAdd(&ccnt[b * CPAD], 1);
        if (p < CAND_CAP) cand[(size_t)b * CAND_CAP + p] = key;
    }
}

// Per-batch exact top-K over the small candidate set (radix select + bitonic sort).
__global__ void k_topk(u64* __restrict__ cand, const int* __restrict__ ccnt,
                       u64* __restrict__ bufA, u64* __restrict__ selected) {
    int b = blockIdx.x;
    int tid = threadIdx.x;
    __shared__ int hist[256];
    __shared__ int sh_split, sh_above, sh_selc, sh_candc;
    u64* sel = selected + b * KSEL;
    u64* pcur = cand + (size_t)b * CAND_CAP;
    u64* pnxt = bufA + (size_t)b * CAND_CAP;
    int n = ccnt[b * CPAD];
    if (n > CAND_CAP) n = CAND_CAP;
    int need = KSEL, nsel = 0;

    for (int byte = 7; byte >= 0; byte--) {
        if (need <= 0) break;
        if (n <= need) {
            for (int idx = tid; idx < n; idx += blockDim.x) sel[nsel + idx] = pcur[idx];
            nsel += n; need -= n; n = 0;
            break;
        }
        hist[tid] = 0;
        __syncthreads();
        int shift = byte * 8;
        for (int idx = tid; idx < n; idx += blockDim.x)
            atomicAdd(&hist[(int)((pcur[idx] >> shift) & 255)], 1);
        __syncthreads();
        if (tid == 0) {
            int above = 0, s = 255;
            for (; s > 0; s--) {
                if (above + hist[s] >= need) break;
                above += hist[s];
            }
            sh_split = s; sh_above = above; sh_selc = 0; sh_candc = 0;
        }
        __syncthreads();
        int s = sh_split;
        for (int idx = tid; idx < n; idx += blockDim.x) {
            u64 e = pcur[idx];
            int bv = (int)((e >> shift) & 255);
            if (bv > s) { int p = atomicAdd(&sh_selc, 1); sel[nsel + p] = e; }
            else if (bv == s) { int p = atomicAdd(&sh_candc, 1); pnxt[p] = e; }
        }
        __syncthreads();
        nsel += sh_above; need -= sh_above; n = sh_candc;
        u64* t = pcur; pcur = pnxt; pnxt = t;
        __syncthreads();
    }
    if (need > 0 && n > 0) {
        int take = need < n ? need : n;
        for (int idx = tid; idx < take; idx += blockDim.x) sel[nsel + idx] = pcur[idx];
        nsel += take;
    }
    for (int idx = nsel + tid; idx < KSEL; idx += blockDim.x) sel[idx] = 0;
    __syncthreads();

    __shared__ u64 sk[KSEL];
    if (tid < KSEL) sk[tid] = sel[tid];
    __syncthreads();
    for (int k = 2; k <= KSEL; k <<= 1) {
        for (int j = k >> 1; j > 0; j >>= 1) {
            if (tid < KSEL) {
                int ixj = tid ^ j;
                if (ixj > tid) {
                    u64 a = sk[tid], c2 = sk[ixj];
                    bool upper = (tid & k) != 0;
                    if (upper ? (a > c2) : (a < c2)) { sk[tid] = c2; sk[ixj] = a; }
                }
            }
            __syncthreads();
        }
    }
    if (tid < KSEL) sel[tid] = sk[tid];
}

// Wave-per-peak finalize: parallel probes, coalesced feats gather, shfl GEMV.
__global__ void k_final(const int* __restrict__ coords, const float* __restrict__ feats,
                        const float* __restrict__ scores, const float* __restrict__ W,
                        const float* __restrict__ bias, const float* __restrict__ background,
                        const u64* __restrict__ tab, const u64* __restrict__ selected,
                        float* __restrict__ out, int N) {
    int gw = (blockIdx.x * blockDim.x + threadIdx.x) >> 6;
    int lane = threadIdx.x & 63;
    float* full = out + NB * KSEL + (size_t)N * 32;
    if (gw >= NB * KSEL) {
        int b = gw - NB * KSEL;
        if (b < NB && lane < 32)
            full[(size_t)(b * (KSEL + 1)) * 32 + lane] = background[lane];
        return;
    }
    int b = gw >> 7, k = gw & 127;
    u64 key = selected[gw];
    float* row = full + (size_t)(b * (KSEL + 1) + 1 + k) * 32;
    if (key == 0ull) {
        if (lane == 0) out[gw] = 0.f;
        if (lane < 32) row[lane] = 0.f;
        return;
    }
    float conf = __uint_as_float((u32)(key >> 32));
    int i = (int)(~(u32)key);
    if (lane == 0) out[gw] = conf;
    int4 c = ((const int4*)coords)[i];
    int kb = ((c.x * S + c.y) * S + c.z) * S + c.w;
    int j = -1; bool hit = false;
    if (lane < 27) {
        int dx = lane / 9 - 1, r = lane % 9;
        int dy = r / 3 - 1, dz = r % 3 - 1;
        int nx = c.y + dx, ny = c.z + dy, nz = c.w + dz;
        if ((unsigned)nx < S && (unsigned)ny < S && (unsigned)nz < S) {
            j = tab_lookup(tab, kb + dx * (S * S) + dy * S + dz);
            if (j >= 0) hit = scores[j] > TAU;
        }
    }
    u64 hm = __ballot(hit);
    int c27 = __popcll(hm);
    float fsum = 0.f;
    u64 m = hm;
    while (m) {
        int src = __ffsll((long long)m) - 1;
        m &= m - 1;
        int jj = __shfl(j, src);
        fsum += feats[(size_t)jj * 64 + lane];
    }
    float favg = fsum / fmaxf((float)c27, 1.0f);
    int d = lane & 31;
    float acc = bias[d];
    #pragma unroll
    for (int l = 0; l < 64; l++) {
        float fl = __shfl(favg, l);
        acc = fmaf(fl, W[l * 32 + d], acc);
    }
    float ss = acc * acc;
    #pragma unroll
    for (int off = 1; off < 32; off <<= 1) ss += __shfl_xor(ss, off);
    float inv = 1.0f / fmaxf(sqrtf(ss), 1e-12f);
    if (lane < 32) row[lane] = acc * inv;
}

extern "C" void kernel_launch(void* const* d_in, const int* in_sizes, int n_in,
                              void* d_out, int out_size, void* d_ws, size_t ws_size,
                              hipStream_t stream) {
    const int* coords = (const int*)d_in[0];
    const float* feats = (const float*)d_in[1];
    const float* scores = (const float*)d_in[2];
    const float* W = (const float*)d_in[3];
    const float* bias = (const float*)d_in[4];
    const float* background = (const float*)d_in[5];
    int N = in_sizes[0] / 4;
    float* out = (float*)d_out;
    int pcap = N / 2;

    char* ws = (char*)d_ws;
    size_t off = 0;
    u64* tab = (u64*)(ws + off); off += (size_t)TAB_SZ * 8;
    size_t zoff = off;
    u64* bmq = (u64*)(ws + off); off += (size_t)BMQ_WORDS * 8;
    int* hist = (int*)(ws + off); off += (size_t)NB * NBINS * 4;
    int* cnt = (int*)(ws + off); off += (size_t)NB * CPAD * 4;
    int* ccnt = (int*)(ws + off); off += (size_t)NB * CPAD * 4;
    int* dcnt = (int*)(ws + off); off += (size_t)CPAD * 4;
    u32* thrbin = (u32*)(ws + off); off += 256;
    u8* claimed = (u8*)(ws + off); off += ((size_t)N + 255) & ~255ull;
    size_t zlen = off - zoff;
    u32* dlist = (u32*)(ws + off); off += (size_t)N * 4;
    u64* peaks = (u64*)(ws + off); off += (size_t)NB * pcap * 8;
    u64* cand = (u64*)(ws + off); off += (size_t)NB * CAND_CAP * 8;
    u64* bufA = (u64*)(ws + off); off += (size_t)NB * CAND_CAP * 8;
    u64* selected = (u64*)(ws + off); off += (size_t)NB * KSEL * 8;

    int nBlk = (N + 255) / 256;            // 3125 insert/peak blocks
    int nDescA = nBlk / 2;                 // 1562 desc blocks in fused1
    int rowsA = nDescA * 256;
    int nDescB = (N - rowsA + 255) / 256;  // 1563 desc blocks in fused2
    int half = (nBlk + 1) / 2;
    int g1 = half > nDescA ? half : nDescA;
    int g2 = half > nDescB ? half : nDescB;

    (void)hipMemsetAsync(tab, 0xFF, (size_t)TAB_SZ * 8, stream);   // EMPTY64
    (void)hipMemsetAsync(ws + zoff, 0, zlen, stream);              // bmq/hist/cnt/ccnt/dcnt/claimed
    k_ins_desc<<<3 * g1, 256, 0, stream>>>(coords, scores, tab, bmq, claimed, dlist, dcnt,
                                           feats, W, bias, out + NB * KSEL,
                                           N, nBlk, nDescA, 0);
    k_fixrep<<<16, 256, 0, stream>>>(dlist, dcnt, claimed);
    k_peak_desc<<<3 * g2, 256, 0, stream>>>(coords, scores, tab, bmq, claimed,
                                            peaks, cnt,
                                            feats, W, bias, out + NB * KSEL,
                                            N, pcap, nBlk, nDescB, rowsA);
    k_hist<<<512, 256, 0, stream>>>(peaks, cnt, hist, pcap);
    k_thresh<<<1, 256, 0, stream>>>(hist, cnt, thrbin, pcap);
    k_compact<<<(NB * pcap + 255) / 256, 256, 0, stream>>>(peaks, cnt, thrbin, cand, ccnt, pcap);
    k_topk<<<NB, 256, 0, stream>>>(cand, ccnt, bufA, selected);
    k_final<<<(NB * KSEL + NB + 3) / 4, 256, 0, stream>>>(coords, feats, scores, W, bias,
                                                          background, tab, selected, out, N);
}

// Round 20
// 302.618 us; speedup vs baseline: 1.0173x; 1.0173x over previous
//
#include <hip/hip_runtime.h>
#include <math.h>

#define S 256
#define NB 4
#define TAU 0.1f
#define KSEL 128
#define LOG_TAB 21
#define TAB_SZ (1u << LOG_TAB)
#define TAB_MASK (TAB_SZ - 1)
#define EMPTY64 0xFFFFFFFFFFFFFFFFull
#define BMQ_WORDS (1u << 20)  // 4*32^3 bricks * 8 u64 words = 8MB
#define NBINS 8192
#define BIN_BASE 0x3D800      // (0x3D800000 >> 12), conf floor 0.0625 < TAU
#define CAND_CAP 4096
#define CPAD 32               // ints per counter slot -> one 128B line each

typedef unsigned long long u64;
typedef unsigned int u32;
typedef unsigned char u8;

__device__ __forceinline__ u32 hash_key(int key) {
    u32 h = (u32)key * 0x9E3779B1u;
    h ^= h >> 15;
    return h & TAB_MASK;
}

__device__ __forceinline__ int conf_bin(float conf) {
    int bin = (int)(__float_as_uint(conf) >> 12) - BIN_BASE;
    return bin < 0 ? 0 : (bin > NBINS - 1 ? NBINS - 1 : bin);
}

__device__ __forceinline__ int tab_lookup(const u64* __restrict__ tab, int key) {
    u32 slot = hash_key(key);
    for (;;) {
        u64 e = tab[slot];
        if ((u32)(e >> 32) == (u32)key) return (int)(u32)e;
        if (e == EMPTY64) return -1;
        slot = (slot + 1) & TAB_MASK;
    }
}

// Custom init: tab=EMPTY64 + zero region, plain 64-bit grid-stride stores.
// Replaces runtime fillBufferAligned (which showed a 119us stall in R19).
__global__ __launch_bounds__(256) void k_init(u64* __restrict__ tab,
                                              u64* __restrict__ zr, size_t zwords) {
    size_t t = (size_t)blockIdx.x * blockDim.x + threadIdx.x;
    size_t stride = (size_t)gridDim.x * blockDim.x;
    for (size_t i = t; i < (size_t)TAB_SZ; i += stride) tab[i] = EMPTY64;
    for (size_t i = t; i < zwords; i += stride) zr[i] = 0ull;
}

// ---- desc row body: register staging (cached loads) + uniform-W GEMV ----
__device__ __forceinline__ void desc_row(const float* __restrict__ feats,
                                         const float* __restrict__ W,
                                         const float* __restrict__ bias,
                                         float* __restrict__ voxel_desc, int i, int N) {
    if (i >= N) return;
    const float4* row4 = (const float4*)(feats + (size_t)i * 64);
    float4 r[16];
    #pragma unroll
    for (int k = 0; k < 16; k++) r[k] = row4[k];
    __builtin_amdgcn_sched_barrier(0);   // keep loads issued before compute
    float acc[32];
    #pragma unroll
    for (int d = 0; d < 32; d++) acc[d] = bias[d];
    #pragma unroll
    for (int k = 0; k < 16; k++) {
        float4 f = r[k];
        const float* Wb = W + k * 4 * 32;   // thread-uniform -> scalar loads
        #pragma unroll
        for (int d = 0; d < 32; d++) {
            acc[d] = fmaf(f.x, Wb[d], acc[d]);
            acc[d] = fmaf(f.y, Wb[32 + d], acc[d]);
            acc[d] = fmaf(f.z, Wb[64 + d], acc[d]);
            acc[d] = fmaf(f.w, Wb[96 + d], acc[d]);
        }
    }
    float ss = 0.f;
    #pragma unroll
    for (int d = 0; d < 32; d++) ss += acc[d] * acc[d];
    float inv = 1.0f / fmaxf(sqrtf(ss), 1e-12f);
    float4* out4 = (float4*)(voxel_desc + (size_t)i * 32);
    #pragma unroll
    for (int q = 0; q < 8; q++) {
        float4 o;
        o.x = acc[q * 4 + 0] * inv; o.y = acc[q * 4 + 1] * inv;
        o.z = acc[q * 4 + 2] * inv; o.w = acc[q * 4 + 3] * inv;
        out4[q] = o;   // thread writes exactly its own 128B line
    }
}

// ---- insert body: CAS-first insert + exact rep-flag tracking + brick bitmap ----
__device__ __forceinline__ void insert_pt(const int* __restrict__ coords,
                                          const float* __restrict__ scores,
                                          u64* __restrict__ tab, u64* __restrict__ bmq,
                                          u8* __restrict__ claimed, u32* __restrict__ dlist,
                                          int* __restrict__ dcnt, int i, int N) {
    if (i >= N) return;
    int4 c = ((const int4*)coords)[i];
    float conf = scores[i];
    int key = ((c.x * S + c.y) * S + c.z) * S + c.w;
    if (conf > TAU) {
        int brick = (((c.x << 5) + (c.y >> 3)) * 32 + (c.z >> 3)) * 32 + (c.w >> 3);
        u64 bit = 1ull << (((c.z & 7) << 3) | (c.w & 7));
        atomicOr(&bmq[(size_t)brick * 8 + (c.y & 7)], bit);
    }
    u64 ins = ((u64)(u32)key << 32) | (u32)i;
    u32 slot = hash_key(key);
    for (;;) {
        u64 prev = atomicCAS(&tab[slot], EMPTY64, ins);
        if (prev == EMPTY64) { claimed[i] = 1; return; }    // claimed empty slot
        if ((u32)(prev >> 32) == (u32)key) {
            u64 old = atomicMin(&tab[slot], ins);
            if ((u32)old > (u32)i) {                        // displaced larger-index rep
                claimed[i] = 1;
                int p = atomicAdd(dcnt, 1);
                dlist[p] = (u32)old;
            }
            return;
        }
        slot = (slot + 1) & TAB_MASK;                       // different key: probe on
    }
}

// Clear flags of displaced former reps (runs between the two fat kernels).
__global__ void k_fixrep(const u32* __restrict__ dlist, const int* __restrict__ dcnt,
                         u8* __restrict__ claimed) {
    int n = *dcnt;
    for (int t = blockIdx.x * blockDim.x + threadIdx.x; t < n; t += gridDim.x * blockDim.x)
        claimed[dlist[t]] = 0;
}

// Fused: role-interleaved insert (2 of 3 blocks) + desc first-half (1 of 3).
__global__ __launch_bounds__(256, 4) void k_ins_desc(const int* __restrict__ coords,
        const float* __restrict__ scores, u64* __restrict__ tab, u64* __restrict__ bmq,
        u8* __restrict__ claimed, u32* __restrict__ dlist, int* __restrict__ dcnt,
        const float* __restrict__ feats, const float* __restrict__ W,
        const float* __restrict__ bias, float* __restrict__ voxel_desc,
        int N, int nIns, int nDesc, int descRow0) {
    int g = blockIdx.x / 3, r = blockIdx.x % 3;
    if (r < 2) {
        int ib = g * 2 + r;
        if (ib >= nIns) return;
        insert_pt(coords, scores, tab, bmq, claimed, dlist, dcnt,
                  ib * 256 + threadIdx.x, N);
    } else {
        if (g >= nDesc) return;
        desc_row(feats, W, bias, voxel_desc, descRow0 + g * 256 + threadIdx.x, N);
    }
}

// ---- peak body: coalesced rep-flag + window-mask brick gather + sparse probes.
// Histogram build lives in k_hist (keeps hot-bin atomics out of this kernel). ----
__device__ __forceinline__ void peak_block(const int* __restrict__ coords,
        const float* __restrict__ scores, const u64* __restrict__ tab,
        const u64* __restrict__ bmq, const u8* __restrict__ claimed,
        u64* __restrict__ peaks, int* __restrict__ cnt,
        int N, int pcap, int pb) {
    int i = pb * 256 + threadIdx.x;
    bool alive = (i < N);
    int ii = alive ? i : 0;
    int4 c = ((const int4*)coords)[ii];
    float conf = alive ? scores[ii] : -1.0f;
    bool isrep = claimed[ii] != 0;   // coalesced byte read (exact rep-ness)
    int X = c.y, Y = c.z, Z = c.w;
    int kb = ((c.x * S + X) * S + Y) * S + Z;
    bool ispeak = false;
    if (alive && conf > TAU) {
        // own-cell contribution: rep-majority needs NO tab lookup
        float hmax = isrep ? conf : scores[tab_lookup(tab, kb)];
        int ylo = Y > 0 ? Y - 1 : 0, yhi = Y < S - 1 ? Y + 1 : S - 1;
        int zlo = Z > 0 ? Z - 1 : 0, zhi = Z < S - 1 ? Z + 1 : S - 1;
        int by0 = ylo >> 3, by1 = yhi >> 3, bz0 = zlo >> 3, bz1 = zhi >> 3;
        #pragma unroll
        for (int dx = -1; dx <= 1; dx++) {
            int nx = X + dx;
            if ((unsigned)nx >= S) continue;
            int bx = nx >> 3, wsel = nx & 7;
            for (int by = by0; by <= by1; by++) {
                int rlo = ylo > by * 8 ? ylo : by * 8;
                int rhi = yhi < by * 8 + 7 ? yhi : by * 8 + 7;
                int nrow = rhi - rlo + 1;          // 1..3
                u64 span = (nrow == 1 ? 0x01ull : nrow == 2 ? 0x0101ull : 0x010101ull)
                           << ((rlo & 7) * 8);
                for (int bz = bz0; bz <= bz1; bz++) {
                    int clo = zlo > bz * 8 ? zlo : bz * 8;
                    int chi = zhi < bz * 8 + 7 ? zhi : bz * 8 + 7;
                    u32 zbits = ((1u << (chi - clo + 1)) - 1) << (clo & 7);
                    u64 mask = (u64)zbits * span;   // rows rlo..rhi, cols clo..chi
                    u64 word = bmq[(size_t)((((c.x << 5) + bx) * 32 + by) * 32 + bz) * 8 + wsel];
                    u64 mm = word & mask;
                    if (dx == 0 && (Y >> 3) == by && (Z >> 3) == bz)
                        mm &= ~(1ull << (((Y & 7) << 3) | (Z & 7)));   // own bit done above
                    while (mm) {
                        int p = __builtin_ctzll(mm);
                        mm &= mm - 1;
                        int ny = (by << 3) | (p >> 3), nz = (bz << 3) | (p & 7);
                        int j = tab_lookup(tab, ((c.x * S + nx) * S + ny) * S + nz);
                        if (j >= 0) hmax = fmaxf(hmax, scores[j]);
                    }
                }
            }
        }
        ispeak = (hmax == conf);
    }

    __shared__ int wcnt[4][NB];
    __shared__ int bbase[NB];
    int w = threadIdx.x >> 6;
    int lane = threadIdx.x & 63;
    u64 lmask_lt = (lane == 63) ? 0x7FFFFFFFFFFFFFFFull : ((1ull << lane) - 1ull);
    u64 mb[NB];
    #pragma unroll
    for (int b = 0; b < NB; b++) {
        mb[b] = __ballot(ispeak && (c.x == b));
        if (lane == 0) wcnt[w][b] = __popcll(mb[b]);
    }
    __syncthreads();
    if (threadIdx.x < NB) {
        int b = threadIdx.x;
        int tot = wcnt[0][b] + wcnt[1][b] + wcnt[2][b] + wcnt[3][b];
        bbase[b] = tot > 0 ? atomicAdd(&cnt[b * CPAD], tot) : 0;
    }
    __syncthreads();
    if (ispeak) {
        int b = c.x;
        int pre = 0;
        for (int w2 = 0; w2 < w; w2++) pre += wcnt[w2][b];
        int rank = __popcll(mb[b] & lmask_lt);
        int pidx = bbase[b] + pre + rank;
        if (pidx < pcap)
            peaks[(size_t)b * pcap + pidx] =
                ((u64)__float_as_uint(conf) << 32) | (u32)(~(u32)i);
    }
}

// Fused: role-interleaved peak (2 of 3 blocks) + desc second-half (1 of 3).
__global__ __launch_bounds__(256, 4) void k_peak_desc(const int* __restrict__ coords,
        const float* __restrict__ scores, const u64* __restrict__ tab,
        const u64* __restrict__ bmq, const u8* __restrict__ claimed,
        u64* __restrict__ peaks, int* __restrict__ cnt,
        const float* __restrict__ feats,
        const float* __restrict__ W, const float* __restrict__ bias,
        float* __restrict__ voxel_desc, int N, int pcap,
        int nPeak, int nDesc, int descRow0) {
    int g = blockIdx.x / 3, r = blockIdx.x % 3;
    if (r < 2) {
        int pb = g * 2 + r;
        if (pb >= nPeak) return;
        peak_block(coords, scores, tab, bmq, claimed, peaks, cnt, N, pcap, pb);
    } else {
        if (g >= nDesc) return;
        desc_row(feats, W, bias, voxel_desc, descRow0 + g * 256 + threadIdx.x, N);
    }
}

// Dedicated histogram build over compacted peaks (dense sequential reads).
__global__ void k_hist(const u64* __restrict__ peaks, const int* __restrict__ cnt,
                       int* __restrict__ hist, int pcap) {
    for (int b = 0; b < NB; b++) {
        int n = cnt[b * CPAD]; if (n > pcap) n = pcap;
        for (int t = blockIdx.x * blockDim.x + threadIdx.x; t < n;
             t += gridDim.x * blockDim.x) {
            float conf = __uint_as_float((u32)(peaks[(size_t)b * pcap + t] >> 32));
            atomicAdd(&hist[b * NBINS + conf_bin(conf)], 1);
        }
    }
}

// One block; wave b finds per-batch threshold bin (count of bins >= thr covers K).
__global__ void k_thresh(const int* __restrict__ hist, const int* __restrict__ cnt,
                         u32* __restrict__ thrbin, int pcap) {
    int w = threadIdx.x >> 6;
    int lane = threadIdx.x & 63;
    if (w >= NB) return;
    int n = cnt[w * CPAD]; if (n > pcap) n = pcap;
    int need = n < KSEL ? n : KSEL;
    const int* h = hist + w * NBINS;
    int running = 0;
    u32 thr = 0;
    for (int hi = NBINS - 64; hi >= 0; hi -= 64) {
        int v = h[hi + lane];
        int s = v;
        #pragma unroll
        for (int off = 1; off < 64; off <<= 1) {
            int o = __shfl_down(s, off);
            if (lane + off < 64) s += o;
        }
        int csum = __shfl(s, 0);
        if (running + csum >= need) {
            u64 m = __ballot(running + s >= need);
            int top = 63 - __builtin_clzll(m);
            thr = (u32)(hi + top);
            break;
        }
        running += csum;
    }
    if (lane == 0) thrbin[w] = thr;
}

__global__ void k_compact(const u64* __restrict__ peaks, const int* __restrict__ cnt,
                          const u32* __restrict__ thrbin, u64* __restrict__ cand,
                          int* __restrict__ ccnt, int pcap) {
    int t = blockIdx.x * blockDim.x + threadIdx.x;
    int b = t / pcap;
    if (b >= NB) return;
    int e = t % pcap;
    int n = cnt[b * CPAD]; if (n > pcap) n = pcap;
    if (e >= n) return;
    u64 key = peaks[(size_t)b * pcap + e];
    float conf = __uint_as_float((u32)(key >> 32));
    if (conf_bin(conf) >= (int)thrbin[b]) {
        int p = atomicAdd(&ccnt[b * CPAD], 1);
        if (p < CAND_CAP) cand[(size_t)b * CAND_CAP + p] = key;
    }
}

// Per-batch exact top-K over the small candidate set (radix select + bitonic sort).
__global__ void k_topk(u64* __restrict__ cand, const int* __restrict__ ccnt,
                       u64* __restrict__ bufA, u64* __restrict__ selected) {
    int b = blockIdx.x;
    int tid = threadIdx.x;
    __shared__ int hist[256];
    __shared__ int sh_split, sh_above, sh_selc, sh_candc;
    u64* sel = selected + b * KSEL;
    u64* pcur = cand + (size_t)b * CAND_CAP;
    u64* pnxt = bufA + (size_t)b * CAND_CAP;
    int n = ccnt[b * CPAD];
    if (n > CAND_CAP) n = CAND_CAP;
    int need = KSEL, nsel = 0;

    for (int byte = 7; byte >= 0; byte--) {
        if (need <= 0) break;
        if (n <= need) {
            for (int idx = tid; idx < n; idx += blockDim.x) sel[nsel + idx] = pcur[idx];
            nsel += n; need -= n; n = 0;
            break;
        }
        hist[tid] = 0;
        __syncthreads();
        int shift = byte * 8;
        for (int idx = tid; idx < n; idx += blockDim.x)
            atomicAdd(&hist[(int)((pcur[idx] >> shift) & 255)], 1);
        __syncthreads();
        if (tid == 0) {
            int above = 0, s = 255;
            for (; s > 0; s--) {
                if (above + hist[s] >= need) break;
                above += hist[s];
            }
            sh_split = s; sh_above = above; sh_selc = 0; sh_candc = 0;
        }
        __syncthreads();
        int s = sh_split;
        for (int idx = tid; idx < n; idx += blockDim.x) {
            u64 e = pcur[idx];
            int bv = (int)((e >> shift) & 255);
            if (bv > s) { int p = atomicAdd(&sh_selc, 1); sel[nsel + p] = e; }
            else if (bv == s) { int p = atomicAdd(&sh_candc, 1); pnxt[p] = e; }
        }
        __syncthreads();
        nsel += sh_above; need -= sh_above; n = sh_candc;
        u64* t = pcur; pcur = pnxt; pnxt = t;
        __syncthreads();
    }
    if (need > 0 && n > 0) {
        int take = need < n ? need : n;
        for (int idx = tid; idx < take; idx += blockDim.x) sel[nsel + idx] = pcur[idx];
        nsel += take;
    }
    for (int idx = nsel + tid; idx < KSEL; idx += blockDim.x) sel[idx] = 0;
    __syncthreads();

    __shared__ u64 sk[KSEL];
    if (tid < KSEL) sk[tid] = sel[tid];
    __syncthreads();
    for (int k = 2; k <= KSEL; k <<= 1) {
        for (int j = k >> 1; j > 0; j >>= 1) {
            if (tid < KSEL) {
                int ixj = tid ^ j;
                if (ixj > tid) {
                    u64 a = sk[tid], c2 = sk[ixj];
                    bool upper = (tid & k) != 0;
                    if (upper ? (a > c2) : (a < c2)) { sk[tid] = c2; sk[ixj] = a; }
                }
            }
            __syncthreads();
        }
    }
    if (tid < KSEL) sel[tid] = sk[tid];
}

// Wave-per-peak finalize: parallel probes, coalesced feats gather, shfl GEMV.
__global__ void k_final(const int* __restrict__ coords, const float* __restrict__ feats,
                        const float* __restrict__ scores, const float* __restrict__ W,
                        const float* __restrict__ bias, const float* __restrict__ background,
                        const u64* __restrict__ tab, const u64* __restrict__ selected,
                        float* __restrict__ out, int N) {
    int gw = (blockIdx.x * blockDim.x + threadIdx.x) >> 6;
    int lane = threadIdx.x & 63;
    float* full = out + NB * KSEL + (size_t)N * 32;
    if (gw >= NB * KSEL) {
        int b = gw - NB * KSEL;
        if (b < NB && lane < 32)
            full[(size_t)(b * (KSEL + 1)) * 32 + lane] = background[lane];
        return;
    }
    int b = gw >> 7, k = gw & 127;
    u64 key = selected[gw];
    float* row = full + (size_t)(b * (KSEL + 1) + 1 + k) * 32;
    if (key == 0ull) {
        if (lane == 0) out[gw] = 0.f;
        if (lane < 32) row[lane] = 0.f;
        return;
    }
    float conf = __uint_as_float((u32)(key >> 32));
    int i = (int)(~(u32)key);
    if (lane == 0) out[gw] = conf;
    int4 c = ((const int4*)coords)[i];
    int kb = ((c.x * S + c.y) * S + c.z) * S + c.w;
    int j = -1; bool hit = false;
    if (lane < 27) {
        int dx = lane / 9 - 1, r = lane % 9;
        int dy = r / 3 - 1, dz = r % 3 - 1;
        int nx = c.y + dx, ny = c.z + dy, nz = c.w + dz;
        if ((unsigned)nx < S && (unsigned)ny < S && (unsigned)nz < S) {
            j = tab_lookup(tab, kb + dx * (S * S) + dy * S + dz);
            if (j >= 0) hit = scores[j] > TAU;
        }
    }
    u64 hm = __ballot(hit);
    int c27 = __popcll(hm);
    float fsum = 0.f;
    u64 m = hm;
    while (m) {
        int src = __ffsll((long long)m) - 1;
        m &= m - 1;
        int jj = __shfl(j, src);
        fsum += feats[(size_t)jj * 64 + lane];
    }
    float favg = fsum / fmaxf((float)c27, 1.0f);
    int d = lane & 31;
    float acc = bias[d];
    #pragma unroll
    for (int l = 0; l < 64; l++) {
        float fl = __shfl(favg, l);
        acc = fmaf(fl, W[l * 32 + d], acc);
    }
    float ss = acc * acc;
    #pragma unroll
    for (int off = 1; off < 32; off <<= 1) ss += __shfl_xor(ss, off);
    float inv = 1.0f / fmaxf(sqrtf(ss), 1e-12f);
    if (lane < 32) row[lane] = acc * inv;
}

extern "C" void kernel_launch(void* const* d_in, const int* in_sizes, int n_in,
                              void* d_out, int out_size, void* d_ws, size_t ws_size,
                              hipStream_t stream) {
    const int* coords = (const int*)d_in[0];
    const float* feats = (const float*)d_in[1];
    const float* scores = (const float*)d_in[2];
    const float* W = (const float*)d_in[3];
    const float* bias = (const float*)d_in[4];
    const float* background = (const float*)d_in[5];
    int N = in_sizes[0] / 4;
    float* out = (float*)d_out;
    int pcap = N / 2;

    char* ws = (char*)d_ws;
    size_t off = 0;
    u64* tab = (u64*)(ws + off); off += (size_t)TAB_SZ * 8;
    size_t zoff = off;
    u64* bmq = (u64*)(ws + off); off += (size_t)BMQ_WORDS * 8;
    int* hist = (int*)(ws + off); off += (size_t)NB * NBINS * 4;
    int* cnt = (int*)(ws + off); off += (size_t)NB * CPAD * 4;
    int* ccnt = (int*)(ws + off); off += (size_t)NB * CPAD * 4;
    int* dcnt = (int*)(ws + off); off += (size_t)CPAD * 4;
    u32* thrbin = (u32*)(ws + off); off += 256;
    u8* claimed = (u8*)(ws + off); off += ((size_t)N + 255) & ~255ull;
    size_t zlen = off - zoff;           // multiple of 8 (all pieces 8B-aligned sizes)
    u32* dlist = (u32*)(ws + off); off += (size_t)N * 4;
    u64* peaks = (u64*)(ws + off); off += (size_t)NB * pcap * 8;
    u64* cand = (u64*)(ws + off); off += (size_t)NB * CAND_CAP * 8;
    u64* bufA = (u64*)(ws + off); off += (size_t)NB * CAND_CAP * 8;
    u64* selected = (u64*)(ws + off); off += (size_t)NB * KSEL * 8;

    int nBlk = (N + 255) / 256;            // 3125 insert/peak blocks
    int nDescA = nBlk / 2;                 // 1562 desc blocks in fused1
    int rowsA = nDescA * 256;
    int nDescB = (N - rowsA + 255) / 256;  // 1563 desc blocks in fused2
    int half = (nBlk + 1) / 2;
    int g1 = half > nDescA ? half : nDescA;
    int g2 = half > nDescB ? half : nDescB;

    k_init<<<2048, 256, 0, stream>>>(tab, (u64*)(ws + zoff), zlen / 8);
    k_ins_desc<<<3 * g1, 256, 0, stream>>>(coords, scores, tab, bmq, claimed, dlist, dcnt,
                                           feats, W, bias, out + NB * KSEL,
                                           N, nBlk, nDescA, 0);
    k_fixrep<<<16, 256, 0, stream>>>(dlist, dcnt, claimed);
    k_peak_desc<<<3 * g2, 256, 0, stream>>>(coords, scores, tab, bmq, claimed,
                                            peaks, cnt,
                                            feats, W, bias, out + NB * KSEL,
                                            N, pcap, nBlk, nDescB, rowsA);
    k_hist<<<512, 256, 0, stream>>>(peaks, cnt, hist, pcap);
    k_thresh<<<1, 256, 0, stream>>>(hist, cnt, thrbin, pcap);
    k_compact<<<(NB * pcap + 255) / 256, 256, 0, stream>>>(peaks, cnt, thrbin, cand, ccnt, pcap);
    k_topk<<<NB, 256, 0, stream>>>(cand, ccnt, bufA, selected);
    k_final<<<(NB * KSEL + NB + 3) / 4, 256, 0, stream>>>(coords, feats, scores, W, bias,
                                                          background, tab, selected, out, N);
}

// Round 21
// 260.892 us; speedup vs baseline: 1.1800x; 1.1599x over previous
//
#include <hip/hip_runtime.h>
#include <math.h>

#define S 256
#define NB 4
#define TAU 0.1f
#define KSEL 128
#define LOG_TAB 21
#define TAB_SZ (1u << LOG_TAB)
#define TAB_MASK (TAB_SZ - 1)
#define EMPTY64 0xFFFFFFFFFFFFFFFFull
#define BMQ_WORDS (1u << 20)  // 4*32^3 bricks * 8 u64 words = 8MB
#define NBINS 8192
#define BIN_BASE 0x3D800      // (0x3D800000 >> 12), conf floor 0.0625 < TAU
#define CAND_CAP 4096
#define CPAD 32               // ints per counter slot -> one 128B line each

typedef unsigned long long u64;
typedef unsigned int u32;
typedef unsigned char u8;

__device__ __forceinline__ u32 hash_key(int key) {
    u32 h = (u32)key * 0x9E3779B1u;
    h ^= h >> 15;
    return h & TAB_MASK;
}

__device__ __forceinline__ int conf_bin(float conf) {
    int bin = (int)(__float_as_uint(conf) >> 12) - BIN_BASE;
    return bin < 0 ? 0 : (bin > NBINS - 1 ? NBINS - 1 : bin);
}

__device__ __forceinline__ int tab_lookup(const u64* __restrict__ tab, int key) {
    u32 slot = hash_key(key);
    for (;;) {
        u64 e = tab[slot];
        if ((u32)(e >> 32) == (u32)key) return (int)(u32)e;
        if (e == EMPTY64) return -1;
        slot = (slot + 1) & TAB_MASK;
    }
}

// ---- desc row body: register staging (cached loads) + uniform-W GEMV ----
__device__ __forceinline__ void desc_row(const float* __restrict__ feats,
                                         const float* __restrict__ W,
                                         const float* __restrict__ bias,
                                         float* __restrict__ voxel_desc, int i, int N) {
    if (i >= N) return;
    const float4* row4 = (const float4*)(feats + (size_t)i * 64);
    float4 r[16];
    #pragma unroll
    for (int k = 0; k < 16; k++) r[k] = row4[k];
    __builtin_amdgcn_sched_barrier(0);   // keep loads issued before compute
    float acc[32];
    #pragma unroll
    for (int d = 0; d < 32; d++) acc[d] = bias[d];
    #pragma unroll
    for (int k = 0; k < 16; k++) {
        float4 f = r[k];
        const float* Wb = W + k * 4 * 32;   // thread-uniform -> scalar loads
        #pragma unroll
        for (int d = 0; d < 32; d++) {
            acc[d] = fmaf(f.x, Wb[d], acc[d]);
            acc[d] = fmaf(f.y, Wb[32 + d], acc[d]);
            acc[d] = fmaf(f.z, Wb[64 + d], acc[d]);
            acc[d] = fmaf(f.w, Wb[96 + d], acc[d]);
        }
    }
    float ss = 0.f;
    #pragma unroll
    for (int d = 0; d < 32; d++) ss += acc[d] * acc[d];
    float inv = 1.0f / fmaxf(sqrtf(ss), 1e-12f);
    float4* out4 = (float4*)(voxel_desc + (size_t)i * 32);
    #pragma unroll
    for (int q = 0; q < 8; q++) {
        float4 o;
        o.x = acc[q * 4 + 0] * inv; o.y = acc[q * 4 + 1] * inv;
        o.z = acc[q * 4 + 2] * inv; o.w = acc[q * 4 + 3] * inv;
        out4[q] = o;   // thread writes exactly its own 128B line
    }
}

// ---- insert body: CAS-first insert + exact rep-flag tracking + brick bitmap ----
__device__ __forceinline__ void insert_pt(const int* __restrict__ coords,
                                          const float* __restrict__ scores,
                                          u64* __restrict__ tab, u64* __restrict__ bmq,
                                          u8* __restrict__ claimed, u32* __restrict__ dlist,
                                          int* __restrict__ dcnt, int i, int N) {
    if (i >= N) return;
    int4 c = ((const int4*)coords)[i];
    float conf = scores[i];
    int key = ((c.x * S + c.y) * S + c.z) * S + c.w;
    if (conf > TAU) {
        int brick = (((c.x << 5) + (c.y >> 3)) * 32 + (c.z >> 3)) * 32 + (c.w >> 3);
        u64 bit = 1ull << (((c.z & 7) << 3) | (c.w & 7));
        atomicOr(&bmq[(size_t)brick * 8 + (c.y & 7)], bit);
    }
    u64 ins = ((u64)(u32)key << 32) | (u32)i;
    u32 slot = hash_key(key);
    for (;;) {
        u64 prev = atomicCAS(&tab[slot], EMPTY64, ins);
        if (prev == EMPTY64) { claimed[i] = 1; return; }    // claimed empty slot
        if ((u32)(prev >> 32) == (u32)key) {
            u64 old = atomicMin(&tab[slot], ins);
            if ((u32)old > (u32)i) {                        // displaced larger-index rep
                claimed[i] = 1;
                int p = atomicAdd(dcnt, 1);
                dlist[p] = (u32)old;
            }
            return;
        }
        slot = (slot + 1) & TAB_MASK;                       // different key: probe on
    }
}

// Clear flags of displaced former reps (runs between the two fat kernels).
__global__ void k_fixrep(const u32* __restrict__ dlist, const int* __restrict__ dcnt,
                         u8* __restrict__ claimed) {
    int n = *dcnt;
    for (int t = blockIdx.x * blockDim.x + threadIdx.x; t < n; t += gridDim.x * blockDim.x)
        claimed[dlist[t]] = 0;
}

// Fused: role-interleaved insert (2 of 3 blocks) + desc first-half (1 of 3).
__global__ __launch_bounds__(256, 4) void k_ins_desc(const int* __restrict__ coords,
        const float* __restrict__ scores, u64* __restrict__ tab, u64* __restrict__ bmq,
        u8* __restrict__ claimed, u32* __restrict__ dlist, int* __restrict__ dcnt,
        const float* __restrict__ feats, const float* __restrict__ W,
        const float* __restrict__ bias, float* __restrict__ voxel_desc,
        int N, int nIns, int nDesc, int descRow0) {
    int g = blockIdx.x / 3, r = blockIdx.x % 3;
    if (r < 2) {
        int ib = g * 2 + r;
        if (ib >= nIns) return;
        insert_pt(coords, scores, tab, bmq, claimed, dlist, dcnt,
                  ib * 256 + threadIdx.x, N);
    } else {
        if (g >= nDesc) return;
        desc_row(feats, W, bias, voxel_desc, descRow0 + g * 256 + threadIdx.x, N);
    }
}

// ---- peak body: coalesced rep-flag + window-mask brick gather + sparse probes
// + in-kernel histogram (R18-proven placement: atomics hide under probe latency) ----
__device__ __forceinline__ void peak_block(const int* __restrict__ coords,
        const float* __restrict__ scores, const u64* __restrict__ tab,
        const u64* __restrict__ bmq, const u8* __restrict__ claimed,
        u64* __restrict__ peaks, int* __restrict__ cnt,
        int* __restrict__ hist, int N, int pcap, int pb) {
    int i = pb * 256 + threadIdx.x;
    bool alive = (i < N);
    int ii = alive ? i : 0;
    int4 c = ((const int4*)coords)[ii];
    float conf = alive ? scores[ii] : -1.0f;
    bool isrep = claimed[ii] != 0;   // coalesced byte read (exact rep-ness)
    int X = c.y, Y = c.z, Z = c.w;
    int kb = ((c.x * S + X) * S + Y) * S + Z;
    bool ispeak = false;
    if (alive && conf > TAU) {
        // own-cell contribution: rep-majority needs NO tab lookup
        float hmax = isrep ? conf : scores[tab_lookup(tab, kb)];
        int ylo = Y > 0 ? Y - 1 : 0, yhi = Y < S - 1 ? Y + 1 : S - 1;
        int zlo = Z > 0 ? Z - 1 : 0, zhi = Z < S - 1 ? Z + 1 : S - 1;
        int by0 = ylo >> 3, by1 = yhi >> 3, bz0 = zlo >> 3, bz1 = zhi >> 3;
        #pragma unroll
        for (int dx = -1; dx <= 1; dx++) {
            int nx = X + dx;
            if ((unsigned)nx >= S) continue;
            int bx = nx >> 3, wsel = nx & 7;
            for (int by = by0; by <= by1; by++) {
                int rlo = ylo > by * 8 ? ylo : by * 8;
                int rhi = yhi < by * 8 + 7 ? yhi : by * 8 + 7;
                int nrow = rhi - rlo + 1;          // 1..3
                u64 span = (nrow == 1 ? 0x01ull : nrow == 2 ? 0x0101ull : 0x010101ull)
                           << ((rlo & 7) * 8);
                for (int bz = bz0; bz <= bz1; bz++) {
                    int clo = zlo > bz * 8 ? zlo : bz * 8;
                    int chi = zhi < bz * 8 + 7 ? zhi : bz * 8 + 7;
                    u32 zbits = ((1u << (chi - clo + 1)) - 1) << (clo & 7);
                    u64 mask = (u64)zbits * span;   // rows rlo..rhi, cols clo..chi
                    u64 word = bmq[(size_t)((((c.x << 5) + bx) * 32 + by) * 32 + bz) * 8 + wsel];
                    u64 mm = word & mask;
                    if (dx == 0 && (Y >> 3) == by && (Z >> 3) == bz)
                        mm &= ~(1ull << (((Y & 7) << 3) | (Z & 7)));   // own bit done above
                    while (mm) {
                        int p = __builtin_ctzll(mm);
                        mm &= mm - 1;
                        int ny = (by << 3) | (p >> 3), nz = (bz << 3) | (p & 7);
                        int j = tab_lookup(tab, ((c.x * S + nx) * S + ny) * S + nz);
                        if (j >= 0) hmax = fmaxf(hmax, scores[j]);
                    }
                }
            }
        }
        ispeak = (hmax == conf);
    }

    if (ispeak) atomicAdd(&hist[c.x * NBINS + conf_bin(conf)], 1);

    __shared__ int wcnt[4][NB];
    __shared__ int bbase[NB];
    int w = threadIdx.x >> 6;
    int lane = threadIdx.x & 63;
    u64 lmask_lt = (lane == 63) ? 0x7FFFFFFFFFFFFFFFull : ((1ull << lane) - 1ull);
    u64 mb[NB];
    #pragma unroll
    for (int b = 0; b < NB; b++) {
        mb[b] = __ballot(ispeak && (c.x == b));
        if (lane == 0) wcnt[w][b] = __popcll(mb[b]);
    }
    __syncthreads();
    if (threadIdx.x < NB) {
        int b = threadIdx.x;
        int tot = wcnt[0][b] + wcnt[1][b] + wcnt[2][b] + wcnt[3][b];
        bbase[b] = tot > 0 ? atomicAdd(&cnt[b * CPAD], tot) : 0;
    }
    __syncthreads();
    if (ispeak) {
        int b = c.x;
        int pre = 0;
        for (int w2 = 0; w2 < w; w2++) pre += wcnt[w2][b];
        int rank = __popcll(mb[b] & lmask_lt);
        int pidx = bbase[b] + pre + rank;
        if (pidx < pcap)
            peaks[(size_t)b * pcap + pidx] =
                ((u64)__float_as_uint(conf) << 32) | (u32)(~(u32)i);
    }
}

// Fused: role-interleaved peak (2 of 3 blocks) + desc second-half (1 of 3).
__global__ __launch_bounds__(256, 4) void k_peak_desc(const int* __restrict__ coords,
        const float* __restrict__ scores, const u64* __restrict__ tab,
        const u64* __restrict__ bmq, const u8* __restrict__ claimed,
        u64* __restrict__ peaks, int* __restrict__ cnt,
        int* __restrict__ hist, const float* __restrict__ feats,
        const float* __restrict__ W, const float* __restrict__ bias,
        float* __restrict__ voxel_desc, int N, int pcap,
        int nPeak, int nDesc, int descRow0) {
    int g = blockIdx.x / 3, r = blockIdx.x % 3;
    if (r < 2) {
        int pb = g * 2 + r;
        if (pb >= nPeak) return;
        peak_block(coords, scores, tab, bmq, claimed, peaks, cnt, hist, N, pcap, pb);
    } else {
        if (g >= nDesc) return;
        desc_row(feats, W, bias, voxel_desc, descRow0 + g * 256 + threadIdx.x, N);
    }
}

// One block; wave b finds per-batch threshold bin (count of bins >= thr covers K).
__global__ void k_thresh(const int* __restrict__ hist, const int* __restrict__ cnt,
                         u32* __restrict__ thrbin, int pcap) {
    int w = threadIdx.x >> 6;
    int lane = threadIdx.x & 63;
    if (w >= NB) return;
    int n = cnt[w * CPAD]; if (n > pcap) n = pcap;
    int need = n < KSEL ? n : KSEL;
    const int* h = hist + w * NBINS;
    int running = 0;
    u32 thr = 0;
    for (int hi = NBINS - 64; hi >= 0; hi -= 64) {
        int v = h[hi + lane];
        int s = v;
        #pragma unroll
        for (int off = 1; off < 64; off <<= 1) {
            int o = __shfl_down(s, off);
            if (lane + off < 64) s += o;
        }
        int csum = __shfl(s, 0);
        if (running + csum >= need) {
            u64 m = __ballot(running + s >= need);
            int top = 63 - __builtin_clzll(m);
            thr = (u32)(hi + top);
            break;
        }
        running += csum;
    }
    if (lane == 0) thrbin[w] = thr;
}

__global__ void k_compact(const u64* __restrict__ peaks, const int* __restrict__ cnt,
                          const u32* __restrict__ thrbin, u64* __restrict__ cand,
                          int* __restrict__ ccnt, int pcap) {
    int t = blockIdx.x * blockDim.x + threadIdx.x;
    int b = t / pcap;
    if (b >= NB) return;
    int e = t % pcap;
    int n = cnt[b * CPAD]; if (n > pcap) n = pcap;
    if (e >= n) return;
    u64 key = peaks[(size_t)b * pcap + e];
    float conf = __uint_as_float((u32)(key >> 32));
    if (conf_bin(conf) >= (int)thrbin[b]) {
        int p = atomicAdd(&ccnt[b * CPAD], 1);
        if (p < CAND_CAP) cand[(size_t)b * CAND_CAP + p] = key;
    }
}

// Per-batch exact top-K over the small candidate set (radix select + bitonic sort).
__global__ void k_topk(u64* __restrict__ cand, const int* __restrict__ ccnt,
                       u64* __restrict__ bufA, u64* __restrict__ selected) {
    int b = blockIdx.x;
    int tid = threadIdx.x;
    __shared__ int hist[256];
    __shared__ int sh_split, sh_above, sh_selc, sh_candc;
    u64* sel = selected + b * KSEL;
    u64* pcur = cand + (size_t)b * CAND_CAP;
    u64* pnxt = bufA + (size_t)b * CAND_CAP;
    int n = ccnt[b * CPAD];
    if (n > CAND_CAP) n = CAND_CAP;
    int need = KSEL, nsel = 0;

    for (int byte = 7; byte >= 0; byte--) {
        if (need <= 0) break;
        if (n <= need) {
            for (int idx = tid; idx < n; idx += blockDim.x) sel[nsel + idx] = pcur[idx];
            nsel += n; need -= n; n = 0;
            break;
        }
        hist[tid] = 0;
        __syncthreads();
        int shift = byte * 8;
        for (int idx = tid; idx < n; idx += blockDim.x)
            atomicAdd(&hist[(int)((pcur[idx] >> shift) & 255)], 1);
        __syncthreads();
        if (tid == 0) {
            int above = 0, s = 255;
            for (; s > 0; s--) {
                if (above + hist[s] >= need) break;
                above += hist[s];
            }
            sh_split = s; sh_above = above; sh_selc = 0; sh_candc = 0;
        }
        __syncthreads();
        int s = sh_split;
        for (int idx = tid; idx < n; idx += blockDim.x) {
            u64 e = pcur[idx];
            int bv = (int)((e >> shift) & 255);
            if (bv > s) { int p = atomicAdd(&sh_selc, 1); sel[nsel + p] = e; }
            else if (bv == s) { int p = atomicAdd(&sh_candc, 1); pnxt[p] = e; }
        }
        __syncthreads();
        nsel += sh_above; need -= sh_above; n = sh_candc;
        u64* t = pcur; pcur = pnxt; pnxt = t;
        __syncthreads();
    }
    if (need > 0 && n > 0) {
        int take = need < n ? need : n;
        for (int idx = tid; idx < take; idx += blockDim.x) sel[nsel + idx] = pcur[idx];
        nsel += take;
    }
    for (int idx = nsel + tid; idx < KSEL; idx += blockDim.x) sel[idx] = 0;
    __syncthreads();

    __shared__ u64 sk[KSEL];
    if (tid < KSEL) sk[tid] = sel[tid];
    __syncthreads();
    for (int k = 2; k <= KSEL; k <<= 1) {
        for (int j = k >> 1; j > 0; j >>= 1) {
            if (tid < KSEL) {
                int ixj = tid ^ j;
                if (ixj > tid) {
                    u64 a = sk[tid], c2 = sk[ixj];
                    bool upper = (tid & k) != 0;
                    if (upper ? (a > c2) : (a < c2)) { sk[tid] = c2; sk[ixj] = a; }
                }
            }
            __syncthreads();
        }
    }
    if (tid < KSEL) sel[tid] = sk[tid];
}

// Wave-per-peak finalize: parallel probes, coalesced feats gather, shfl GEMV.
__global__ void k_final(const int* __restrict__ coords, const float* __restrict__ feats,
                        const float* __restrict__ scores, const float* __restrict__ W,
                        const float* __restrict__ bias, const float* __restrict__ background,
                        const u64* __restrict__ tab, const u64* __restrict__ selected,
                        float* __restrict__ out, int N) {
    int gw = (blockIdx.x * blockDim.x + threadIdx.x) >> 6;
    int lane = threadIdx.x & 63;
    float* full = out + NB * KSEL + (size_t)N * 32;
    if (gw >= NB * KSEL) {
        int b = gw - NB * KSEL;
        if (b < NB && lane < 32)
            full[(size_t)(b * (KSEL + 1)) * 32 + lane] = background[lane];
        return;
    }
    int b = gw >> 7, k = gw & 127;
    u64 key = selected[gw];
    float* row = full + (size_t)(b * (KSEL + 1) + 1 + k) * 32;
    if (key == 0ull) {
        if (lane == 0) out[gw] = 0.f;
        if (lane < 32) row[lane] = 0.f;
        return;
    }
    float conf = __uint_as_float((u32)(key >> 32));
    int i = (int)(~(u32)key);
    if (lane == 0) out[gw] = conf;
    int4 c = ((const int4*)coords)[i];
    int kb = ((c.x * S + c.y) * S + c.z) * S + c.w;
    int j = -1; bool hit = false;
    if (lane < 27) {
        int dx = lane / 9 - 1, r = lane % 9;
        int dy = r / 3 - 1, dz = r % 3 - 1;
        int nx = c.y + dx, ny = c.z + dy, nz = c.w + dz;
        if ((unsigned)nx < S && (unsigned)ny < S && (unsigned)nz < S) {
            j = tab_lookup(tab, kb + dx * (S * S) + dy * S + dz);
            if (j >= 0) hit = scores[j] > TAU;
        }
    }
    u64 hm = __ballot(hit);
    int c27 = __popcll(hm);
    float fsum = 0.f;
    u64 m = hm;
    while (m) {
        int src = __ffsll((long long)m) - 1;
        m &= m - 1;
        int jj = __shfl(j, src);
        fsum += feats[(size_t)jj * 64 + lane];
    }
    float favg = fsum / fmaxf((float)c27, 1.0f);
    int d = lane & 31;
    float acc = bias[d];
    #pragma unroll
    for (int l = 0; l < 64; l++) {
        float fl = __shfl(favg, l);
        acc = fmaf(fl, W[l * 32 + d], acc);
    }
    float ss = acc * acc;
    #pragma unroll
    for (int off = 1; off < 32; off <<= 1) ss += __shfl_xor(ss, off);
    float inv = 1.0f / fmaxf(sqrtf(ss), 1e-12f);
    if (lane < 32) row[lane] = acc * inv;
}

extern "C" void kernel_launch(void* const* d_in, const int* in_sizes, int n_in,
                              void* d_out, int out_size, void* d_ws, size_t ws_size,
                              hipStream_t stream) {
    const int* coords = (const int*)d_in[0];
    const float* feats = (const float*)d_in[1];
    const float* scores = (const float*)d_in[2];
    const float* W = (const float*)d_in[3];
    const float* bias = (const float*)d_in[4];
    const float* background = (const float*)d_in[5];
    int N = in_sizes[0] / 4;
    float* out = (float*)d_out;
    int pcap = N / 2;

    char* ws = (char*)d_ws;
    size_t off = 0;
    u64* tab = (u64*)(ws + off); off += (size_t)TAB_SZ * 8;
    size_t zoff = off;
    u64* bmq = (u64*)(ws + off); off += (size_t)BMQ_WORDS * 8;
    int* hist = (int*)(ws + off); off += (size_t)NB * NBINS * 4;
    int* cnt = (int*)(ws + off); off += (size_t)NB * CPAD * 4;
    int* ccnt = (int*)(ws + off); off += (size_t)NB * CPAD * 4;
    int* dcnt = (int*)(ws + off); off += (size_t)CPAD * 4;
    u32* thrbin = (u32*)(ws + off); off += 256;
    u8* claimed = (u8*)(ws + off); off += ((size_t)N + 255) & ~255ull;
    size_t zlen = off - zoff;
    u32* dlist = (u32*)(ws + off); off += (size_t)N * 4;
    u64* peaks = (u64*)(ws + off); off += (size_t)NB * pcap * 8;
    u64* cand = (u64*)(ws + off); off += (size_t)NB * CAND_CAP * 8;
    u64* bufA = (u64*)(ws + off); off += (size_t)NB * CAND_CAP * 8;
    u64* selected = (u64*)(ws + off); off += (size_t)NB * KSEL * 8;

    int nBlk = (N + 255) / 256;            // 3125 insert/peak blocks
    int nDescA = nBlk / 2;                 // 1562 desc blocks in fused1
    int rowsA = nDescA * 256;
    int nDescB = (N - rowsA + 255) / 256;  // 1563 desc blocks in fused2
    int half = (nBlk + 1) / 2;
    int g1 = half > nDescA ? half : nDescA;
    int g2 = half > nDescB ? half : nDescB;

    (void)hipMemsetAsync(tab, 0xFF, (size_t)TAB_SZ * 8, stream);   // EMPTY64
    (void)hipMemsetAsync(ws + zoff, 0, zlen, stream);              // bmq/hist/cnt/ccnt/dcnt/claimed
    k_ins_desc<<<3 * g1, 256, 0, stream>>>(coords, scores, tab, bmq, claimed, dlist, dcnt,
                                           feats, W, bias, out + NB * KSEL,
                                           N, nBlk, nDescA, 0);
    k_fixrep<<<16, 256, 0, stream>>>(dlist, dcnt, claimed);
    k_peak_desc<<<3 * g2, 256, 0, stream>>>(coords, scores, tab, bmq, claimed,
                                            peaks, cnt, hist,
                                            feats, W, bias, out + NB * KSEL,
                                            N, pcap, nBlk, nDescB, rowsA);
    k_thresh<<<1, 256, 0, stream>>>(hist, cnt, thrbin, pcap);
    k_compact<<<(NB * pcap + 255) / 256, 256, 0, stream>>>(peaks, cnt, thrbin, cand, ccnt, pcap);
    k_topk<<<NB, 256, 0, stream>>>(cand, ccnt, bufA, selected);
    k_final<<<(NB * KSEL + NB + 3) / 4, 256, 0, stream>>>(coords, feats, scores, W, bias,
                                                          background, tab, selected, out, N);
}